// Round 8
// baseline (477.466 us; speedup 1.0000x reference)
//
#include <hip/hip_runtime.h>

#define DIM   2048
#define LSEQ  4096
#define BATCH 4
#define NTOK  (BATCH*LSEQ)        // 16384
#define NCH   16
#define CHL   (LSEQ/NCH)          // 256
#define PI_F  3.14159265358979f
#define NT    (DIM/64)            // 32 K-tiles of 64

typedef __bf16 bf16x8 __attribute__((ext_vector_type(8)));
typedef float  f32x4  __attribute__((ext_vector_type(4)));
typedef float  f32x8  __attribute__((ext_vector_type(8)));
typedef unsigned short ushort4_t __attribute__((ext_vector_type(4)));
typedef unsigned short ushort8 __attribute__((ext_vector_type(8)));

__device__ __forceinline__ unsigned short f2bf(float f) {
    unsigned int u = __float_as_uint(f);
    u += 0x7fffu + ((u >> 16) & 1u);       // round-to-nearest-even
    return (unsigned short)(u >> 16);
}
__device__ __forceinline__ float bf2f(unsigned short u) {
    return __uint_as_float((unsigned int)u << 16);
}

__device__ __forceinline__ void gload_lds16(const void* g, void* l) {
    __builtin_amdgcn_global_load_lds(
        (const __attribute__((address_space(1))) void*)g,
        (__attribute__((address_space(3))) void*)l, 16, 0, 0);
}

// ---------------- W [K][N] fp32 -> W^T [N][K] bf16 ----------------
__global__ __launch_bounds__(256) void k_transpose(const float* __restrict__ src,
                                                   unsigned short* __restrict__ dst) {
    __shared__ float tile[32][33];
    int tx = threadIdx.x, ty = threadIdx.y;
    int k0 = blockIdx.y * 32, n0 = blockIdx.x * 32;
#pragma unroll
    for (int r = 0; r < 4; r++)
        tile[ty + r * 8][tx] = src[(size_t)(k0 + ty + r * 8) * DIM + n0 + tx];
    __syncthreads();
#pragma unroll
    for (int r = 0; r < 4; r++)
        dst[(size_t)(n0 + ty + r * 8) * DIM + k0 + tx] = f2bf(tile[tx][ty + r * 8]);
}

// ---------------- W_paT[16][2048] bf16 : rows 0..7 = Wp cols, 8..15 = Wa cols ----------------
__global__ __launch_bounds__(256) void k_prep_wpa(const float* __restrict__ Wp,
                                                  const float* __restrict__ Wa,
                                                  unsigned short* __restrict__ WpaT) {
    int idx = blockIdx.x * 256 + threadIdx.x;        // 128 blocks x 256 = 32768
    int p = idx >> 11, k = idx & (DIM - 1);
    float v = (p < 8) ? Wp[(size_t)k * 8 + p] : Wa[(size_t)k * 8 + (p - 8)];
    WpaT[idx] = f2bf(v);
}

// ---- sproj via MFMA: Z = x @ [Wp|Wa] (16-wide), fused x->bf16 emit ----
__global__ __launch_bounds__(256) void k_sproj_mfma(const float* __restrict__ x,
                                                    const unsigned short* __restrict__ WpaT,
                                                    const float* __restrict__ bp,
                                                    const float* __restrict__ ba,
                                                    float* __restrict__ s,
                                                    unsigned short* __restrict__ xbf) {
    const int t = threadIdx.x;
    const int w = t >> 6, l = t & 63;
    const int r16 = l & 15, q = l >> 4;
    const int rowbase = blockIdx.x * 64 + w * 16;
    const float* xr = x + (size_t)(rowbase + r16) * DIM + q * 8;
    unsigned short* xw = xbf + (size_t)(rowbase + r16) * DIM + q * 8;
    const unsigned short* wrow = WpaT + r16 * DIM + q * 8;

    f32x4 acc = {};
#pragma unroll 8
    for (int ks = 0; ks < 64; ks++) {
        f32x8 xv = *(const f32x8*)(xr + ks * 32);
        ushort8 xo;
#pragma unroll
        for (int j = 0; j < 8; j++) xo[j] = f2bf(xv[j]);
        *(ushort8*)(xw + ks * 32) = xo;
        bf16x8 av = *(const bf16x8*)&xo;
        bf16x8 bv = *(const bf16x8*)(wrow + ks * 32);
        acc = __builtin_amdgcn_mfma_f32_16x16x32_bf16(av, bv, acc, 0, 0, 0);
    }
    // acc[j] = Z[rowbase + q*4 + j][col=r16]; cols 0..7 = zp, 8..15 = za
    const float bpv = bp[r16 & 7], bav = ba[r16 & 7];
#pragma unroll
    for (int j = 0; j < 4; j++) {
        float z = acc[j];
        float zo = __shfl_xor(z, 8);            // partner col r16^8
        float zp = z + bpv, za = zo + bav;
        float ph = tanhf(zp) * PI_F;
        float amp = (za > 20.f ? za : log1pf(expf(za))) + 0.1f;
        float term = (r16 < 8) ? (cosf(ph) + sinf(ph)) * amp : 0.f;
        term += __shfl_xor(term, 1);
        term += __shfl_xor(term, 2);
        term += __shfl_xor(term, 4);
        if (r16 == 0) s[rowbase + q * 4 + j] = term;
    }
}

// ---------------- 256x256 bf16 MFMA GEMM, 2 phases/K-tile, SWAPPED operands ----------------
// mfma(bF, aF): C-frag row-dim = B-col (N), col-dim = A-row (M).
// Thread (q,r16) holds C rows r16+16*mi (M), cols q*4+j (N) -> dwordx4/x2 stores (no RMW).
// LDS [slot][kh][256 rows][32 k]; 16B-unit XOR swizzle phys_q = q ^ ((row>>1)&3) (conflicts=0).
// EPI==0: bound_bf = (A@B + bias[c]) * sc[r] as bf16, + fused column sums -> part.
// EPI==1: out = A@B + bias[c] + bf2f(resid_bf[r][c]) as fp32.
__device__ __forceinline__ void stage_unit(const unsigned short* __restrict__ src,
                                           unsigned short* dst, int tid) {
    gload_lds16(src,                     dst + tid * 8);
    gload_lds16(src + (size_t)128 * DIM, dst + (tid + 512) * 8);
}

template <int EPI>
__global__ __launch_bounds__(512, 2) void k_gemm256(const unsigned short* __restrict__ A,
                                                    const unsigned short* __restrict__ Bt,
                                                    const float* __restrict__ bias,
                                                    const float* __restrict__ sc,
                                                    const unsigned short* __restrict__ residbf,
                                                    float* __restrict__ C,
                                                    unsigned short* __restrict__ Cbf,
                                                    float* __restrict__ part) {
    __shared__ __align__(16) unsigned short As[2][2][256 * 32];
    __shared__ __align__(16) unsigned short Bs[2][2][256 * 32];
    __shared__ float colsum[2][256];
    const int tid = threadIdx.x;
    const int w = tid >> 6, lane = tid & 63;
    const int wm = w >> 2, wn = w & 3;
    const int r16 = lane & 15, q = lane >> 4;

    int bid = blockIdx.x;
    int wgs = (bid & 7) * 64 + (bid >> 3);        // bijective XCD swizzle (512 % 8 == 0)
    int tm = wgs >> 3, tn = wgs & 7;
    int brow = tm * 256, bcol = tn * 256;

    const int kq = ((tid & 3) ^ ((tid >> 3) & 3)) * 8;
    const unsigned short* pA = A  + (size_t)(brow + (tid >> 2)) * DIM + kq;
    const unsigned short* pB = Bt + (size_t)(bcol + (tid >> 2)) * DIM + kq;

    const int qs8 = (q ^ ((r16 >> 1) & 3)) * 8;
    const int offA = (wm * 128 + r16) * 32 + qs8;   // 8 M-frags at +i*512
    const int offB = (wn * 64  + r16) * 32 + qs8;   // 4 N-frags at +n*512

    f32x4 acc[4][8] = {};   // [nf][mi]

    // prologue: A-K0(0), B-K0(0), A-K1(0), B-K1(0), A-K0(1) = 10 loads in flight
    stage_unit(pA,      &As[0][0][0], tid);
    stage_unit(pB,      &Bs[0][0][0], tid);
    stage_unit(pA + 32, &As[0][1][0], tid);
    stage_unit(pB + 32, &Bs[0][1][0], tid);
    stage_unit(pA + 64, &As[1][0][0], tid);
    asm volatile("s_waitcnt vmcnt(6)" ::: "memory");    // K0(0) pair landed
    __builtin_amdgcn_s_barrier();

#pragma unroll 2
    for (int t = 0; t < NT; ++t) {
        const int s = t & 1;
        bf16x8 aF[8], bF[4];

        // ---- phase 0: K-half 0 ----
#pragma unroll
        for (int i = 0; i < 8; i++) aF[i] = *(const bf16x8*)(&As[s][0][0] + offA + i * 512);
#pragma unroll
        for (int n = 0; n < 4; n++) bF[n] = *(const bf16x8*)(&Bs[s][0][0] + offB + n * 512);
        stage_unit(pB + (t + 1) * 64,      &Bs[s ^ 1][0][0], tid);   // B-K0(t+1)
        stage_unit(pA + (t + 1) * 64 + 32, &As[s ^ 1][1][0], tid);   // A-K1(t+1)
        __builtin_amdgcn_s_setprio(1);
#pragma unroll
        for (int n = 0; n < 4; n++)
#pragma unroll
            for (int i = 0; i < 8; i++)
                acc[n][i] = __builtin_amdgcn_mfma_f32_16x16x32_bf16(bF[n], aF[i], acc[n][i], 0, 0, 0);
        __builtin_amdgcn_s_setprio(0);
        asm volatile("s_waitcnt vmcnt(4)" ::: "memory"); // prev phase's units landed
        __builtin_amdgcn_s_barrier();

        // ---- phase 1: K-half 1 ----
#pragma unroll
        for (int i = 0; i < 8; i++) aF[i] = *(const bf16x8*)(&As[s][1][0] + offA + i * 512);
#pragma unroll
        for (int n = 0; n < 4; n++) bF[n] = *(const bf16x8*)(&Bs[s][1][0] + offB + n * 512);
        stage_unit(pB + (t + 1) * 64 + 32, &Bs[s ^ 1][1][0], tid);   // B-K1(t+1)
        stage_unit(pA + (t + 2) * 64,      &As[s][0][0], tid);       // A-K0(t+2), own slot K0
        __builtin_amdgcn_s_setprio(1);
#pragma unroll
        for (int n = 0; n < 4; n++)
#pragma unroll
            for (int i = 0; i < 8; i++)
                acc[n][i] = __builtin_amdgcn_mfma_f32_16x16x32_bf16(bF[n], aF[i], acc[n][i], 0, 0, 0);
        __builtin_amdgcn_s_setprio(0);
        asm volatile("s_waitcnt vmcnt(4)" ::: "memory"); // phase-0 units landed
        __builtin_amdgcn_s_barrier();
    }
    asm volatile("s_waitcnt vmcnt(0)" ::: "memory");      // retire phantom tail gloads

    // epilogue (swapped frag): row = brow + wm*128 + mi*16 + r16, col = bcol + wn*64 + nf*16 + q*4 + j
    float cs[4][4] = {};
#pragma unroll
    for (int nf = 0; nf < 4; nf++) {
        const int c0 = bcol + wn * 64 + nf * 16 + q * 4;
        const f32x4 b4 = *(const f32x4*)(bias + c0);
#pragma unroll
        for (int mi = 0; mi < 8; mi++) {
            const int r = brow + wm * 128 + mi * 16 + r16;
            if (EPI == 0) {
                const float scr = sc[r];
                ushort4_t o;
#pragma unroll
                for (int j = 0; j < 4; j++) {
                    float v = (acc[nf][mi][j] + b4[j]) * scr;
                    cs[nf][j] += v;
                    o[j] = f2bf(v);
                }
                *(ushort4_t*)(Cbf + (size_t)r * DIM + c0) = o;          // 8B store
            } else {
                ushort4_t rsd = *(const ushort4_t*)(residbf + (size_t)r * DIM + c0);
                f32x4 v;
#pragma unroll
                for (int j = 0; j < 4; j++) v[j] = acc[nf][mi][j] + b4[j] + bf2f(rsd[j]);
                *(f32x4*)(C + (size_t)r * DIM + c0) = v;                // 16B store
            }
        }
    }
    if (EPI == 0) {   // fused scan_partial: reduce over rows (lane bits 0-3 = r16) then wm
#pragma unroll
        for (int nf = 0; nf < 4; nf++)
#pragma unroll
            for (int j = 0; j < 4; j++) {
                float v = cs[nf][j];
                v += __shfl_xor(v, 1);
                v += __shfl_xor(v, 2);
                v += __shfl_xor(v, 4);
                v += __shfl_xor(v, 8);
                cs[nf][j] = v;
            }
        if (r16 == 0) {
#pragma unroll
            for (int nf = 0; nf < 4; nf++) {
                f32x4 o;
#pragma unroll
                for (int j = 0; j < 4; j++) o[j] = cs[nf][j];
                *(f32x4*)(&colsum[wm][wn * 64 + nf * 16 + q * 4]) = o;
            }
        }
        __syncthreads();
        if (tid < 256)
            part[(size_t)(brow >> 8) * DIM + bcol + tid] = colsum[0][tid] + colsum[1][tid];
    }
}

// ---------------- cumsum over L: chunk-offset scan + apply ----------------
__global__ __launch_bounds__(256) void k_scan_offsets(float* __restrict__ part) {
    int tid = blockIdx.x * 256 + threadIdx.x;  // (b, d)
    int d = tid & (DIM - 1);
    int b = tid >> 11;
    float run = 0.f;
    for (int ch = 0; ch < NCH; ch++) {
        size_t idx = ((size_t)b * NCH + ch) * DIM + d;
        float v = part[idx];
        part[idx] = run;
        run += v;
    }
}

__global__ __launch_bounds__(256) void k_scan_apply(const unsigned short* __restrict__ boundbf,
                                                    const float* __restrict__ part,
                                                    float* __restrict__ ret) {
    int tid = blockIdx.x * 256 + threadIdx.x;
    int d = tid & (DIM - 1);
    int ch = (tid >> 11) & (NCH - 1);
    int b = tid >> 15;
    float run = part[tid];
    size_t base = ((size_t)b * LSEQ + (size_t)ch * CHL) * DIM + d;
    const unsigned short* p = boundbf + base;
    float* o = ret + base;
    for (int i = 0; i < CHL; i++) {
        run += bf2f(p[(size_t)i * DIM]);
        o[(size_t)i * DIM] = run;
    }
}

// ---------------- LayerNorm(retrieved/64) -> h bf16 ----------------
__global__ __launch_bounds__(256) void k_lnorm(const float* __restrict__ ret,
                                               const float* __restrict__ g,
                                               const float* __restrict__ bta,
                                               unsigned short* __restrict__ h) {
    int row = blockIdx.x, t = threadIdx.x;
    const float4* r4 = (const float4*)(ret + (size_t)row * DIM);
    float4 v0 = r4[2 * t], v1 = r4[2 * t + 1];
    const float scl = 1.0f / 64.0f;   // 1/sqrt(L)
    v0.x *= scl; v0.y *= scl; v0.z *= scl; v0.w *= scl;
    v1.x *= scl; v1.y *= scl; v1.z *= scl; v1.w *= scl;
    float sum = v0.x + v0.y + v0.z + v0.w + v1.x + v1.y + v1.z + v1.w;
    float ss  = v0.x*v0.x + v0.y*v0.y + v0.z*v0.z + v0.w*v0.w
              + v1.x*v1.x + v1.y*v1.y + v1.z*v1.z + v1.w*v1.w;
#pragma unroll
    for (int off = 32; off; off >>= 1) { sum += __shfl_down(sum, off); ss += __shfl_down(ss, off); }
    __shared__ float red[4][2];
    __shared__ float mu_s, rstd_s;
    int w = t >> 6, lane = t & 63;
    if (lane == 0) { red[w][0] = sum; red[w][1] = ss; }
    __syncthreads();
    if (t == 0) {
        float S = red[0][0] + red[1][0] + red[2][0] + red[3][0];
        float Q = red[0][1] + red[1][1] + red[2][1] + red[3][1];
        float mu = S / DIM;
        float var = Q / DIM - mu * mu;
        mu_s = mu; rstd_s = rsqrtf(var + 1e-5f);
    }
    __syncthreads();
    float mu = mu_s, rstd = rstd_s;
    f32x8 gv = *(const f32x8*)(g + t * 8);
    f32x8 bv = *(const f32x8*)(bta + t * 8);
    float vv[8] = { v0.x, v0.y, v0.z, v0.w, v1.x, v1.y, v1.z, v1.w };
    ushort8 o;
#pragma unroll
    for (int j = 0; j < 8; j++) o[j] = f2bf((vv[j] - mu) * rstd * gv[j] + bv[j]);
    *(ushort8*)(h + (size_t)row * DIM + t * 8) = o;
}

extern "C" void kernel_launch(void* const* d_in, const int* in_sizes, int n_in,
                              void* d_out, int out_size, void* d_ws, size_t ws_size,
                              hipStream_t stream) {
    const float* x   = (const float*)d_in[0];
    const float* Wp  = (const float*)d_in[1];
    const float* bp  = (const float*)d_in[2];
    const float* Wa  = (const float*)d_in[3];
    const float* ba  = (const float*)d_in[4];
    const float* Wv  = (const float*)d_in[5];
    const float* bv  = (const float*)d_in[6];
    const float* lng = (const float*)d_in[7];
    const float* lnb = (const float*)d_in[8];
    const float* Wo  = (const float*)d_in[9];
    const float* bo  = (const float*)d_in[10];
    float* out = (float*)d_out;

    char* ws = (char*)d_ws;
    unsigned short* x_bf  = (unsigned short*)ws; ws += (size_t)NTOK * DIM * 2;   // bf16 x (A0, resid1)
    unsigned short* h_bf  = (unsigned short*)ws; ws += (size_t)NTOK * DIM * 2;   // lnorm out (A1)
    unsigned short* WvT   = (unsigned short*)ws; ws += (size_t)DIM * DIM * 2;
    unsigned short* WoT   = (unsigned short*)ws; ws += (size_t)DIM * DIM * 2;
    unsigned short* WpaT  = (unsigned short*)ws; ws += (size_t)16 * DIM * 2;
    float* svec           = (float*)ws;          ws += (size_t)NTOK * 4;
    unsigned short* bound = (unsigned short*)ws; ws += (size_t)NTOK * DIM * 2;   // bf16 bound
    float* part           = (float*)ws;          ws += (size_t)BATCH * NCH * DIM * 4;
    float* ret            = out;                 // stage retrieved in d_out, overwritten by GEMM1

    dim3 tb(32, 8);
    k_transpose<<<dim3(64, 64), tb, 0, stream>>>(Wv, WvT);
    k_transpose<<<dim3(64, 64), tb, 0, stream>>>(Wo, WoT);
    k_prep_wpa<<<128, 256, 0, stream>>>(Wp, Wa, WpaT);
    k_sproj_mfma<<<NTOK / 64, 256, 0, stream>>>(x, WpaT, bp, ba, svec, x_bf);

    k_gemm256<0><<<512, 512, 0, stream>>>(x_bf, WvT, bv, svec, nullptr, nullptr, bound, part);

    k_scan_offsets<<<BATCH * DIM / 256, 256, 0, stream>>>(part);
    k_scan_apply<<<BATCH * NCH * DIM / 256, 256, 0, stream>>>(bound, part, ret);

    k_lnorm<<<NTOK, 256, 0, stream>>>(ret, lng, lnb, h_bf);

    k_gemm256<1><<<512, 512, 0, stream>>>(h_bf, WoT, bo, nullptr, x_bf, out, nullptr, nullptr);
}

// Round 9
// 461.053 us; speedup vs baseline: 1.0356x; 1.0356x over previous
//
#include <hip/hip_runtime.h>

#define DIM   2048
#define LSEQ  4096
#define BATCH 4
#define NTOK  (BATCH*LSEQ)        // 16384
#define NCH   16
#define CHL   (LSEQ/NCH)          // 256
#define PI_F  3.14159265358979f
#define NT    (DIM/64)            // 32 K-tiles of 64

typedef __bf16 bf16x8 __attribute__((ext_vector_type(8)));
typedef float  f32x4  __attribute__((ext_vector_type(4)));
typedef float  f32x8  __attribute__((ext_vector_type(8)));
typedef unsigned short ushort4_t __attribute__((ext_vector_type(4)));
typedef unsigned short ushort8 __attribute__((ext_vector_type(8)));

__device__ __forceinline__ unsigned short f2bf(float f) {
    unsigned int u = __float_as_uint(f);
    u += 0x7fffu + ((u >> 16) & 1u);       // round-to-nearest-even
    return (unsigned short)(u >> 16);
}
__device__ __forceinline__ float bf2f(unsigned short u) {
    return __uint_as_float((unsigned int)u << 16);
}

__device__ __forceinline__ void gload_lds16(const void* g, void* l) {
    __builtin_amdgcn_global_load_lds(
        (const __attribute__((address_space(1))) void*)g,
        (__attribute__((address_space(3))) void*)l, 16, 0, 0);
}

// ---------------- W [K][N] fp32 -> W^T [N][K] bf16 ----------------
__global__ __launch_bounds__(256) void k_transpose(const float* __restrict__ src,
                                                   unsigned short* __restrict__ dst) {
    __shared__ float tile[32][33];
    int tx = threadIdx.x, ty = threadIdx.y;
    int k0 = blockIdx.y * 32, n0 = blockIdx.x * 32;
#pragma unroll
    for (int r = 0; r < 4; r++)
        tile[ty + r * 8][tx] = src[(size_t)(k0 + ty + r * 8) * DIM + n0 + tx];
    __syncthreads();
#pragma unroll
    for (int r = 0; r < 4; r++)
        dst[(size_t)(n0 + ty + r * 8) * DIM + k0 + tx] = f2bf(tile[tx][ty + r * 8]);
}

// ---------------- W_paT[16][2048] bf16 : rows 0..7 = Wp cols, 8..15 = Wa cols ----------------
__global__ __launch_bounds__(256) void k_prep_wpa(const float* __restrict__ Wp,
                                                  const float* __restrict__ Wa,
                                                  unsigned short* __restrict__ WpaT) {
    int idx = blockIdx.x * 256 + threadIdx.x;        // 128 blocks x 256 = 32768
    int p = idx >> 11, k = idx & (DIM - 1);
    float v = (p < 8) ? Wp[(size_t)k * 8 + p] : Wa[(size_t)k * 8 + (p - 8)];
    WpaT[idx] = f2bf(v);
}

// ---- sproj via MFMA: Z = x @ [Wp|Wa] (16-wide), fused x->bf16 emit ----
__global__ __launch_bounds__(256) void k_sproj_mfma(const float* __restrict__ x,
                                                    const unsigned short* __restrict__ WpaT,
                                                    const float* __restrict__ bp,
                                                    const float* __restrict__ ba,
                                                    float* __restrict__ s,
                                                    unsigned short* __restrict__ xbf) {
    const int t = threadIdx.x;
    const int w = t >> 6, l = t & 63;
    const int r16 = l & 15, q = l >> 4;
    const int rowbase = blockIdx.x * 64 + w * 16;
    const float* xr = x + (size_t)(rowbase + r16) * DIM + q * 8;
    unsigned short* xw = xbf + (size_t)(rowbase + r16) * DIM + q * 8;
    const unsigned short* wrow = WpaT + r16 * DIM + q * 8;

    f32x4 acc = {};
#pragma unroll 8
    for (int ks = 0; ks < 64; ks++) {
        f32x8 xv = *(const f32x8*)(xr + ks * 32);
        ushort8 xo;
#pragma unroll
        for (int j = 0; j < 8; j++) xo[j] = f2bf(xv[j]);
        *(ushort8*)(xw + ks * 32) = xo;
        bf16x8 av = *(const bf16x8*)&xo;
        bf16x8 bv = *(const bf16x8*)(wrow + ks * 32);
        acc = __builtin_amdgcn_mfma_f32_16x16x32_bf16(av, bv, acc, 0, 0, 0);
    }
    // acc[j] = Z[rowbase + q*4 + j][col=r16]; cols 0..7 = zp, 8..15 = za
    const float bpv = bp[r16 & 7], bav = ba[r16 & 7];
#pragma unroll
    for (int j = 0; j < 4; j++) {
        float z = acc[j];
        float zo = __shfl_xor(z, 8);            // partner col r16^8
        float zp = z + bpv, za = zo + bav;
        float ph = tanhf(zp) * PI_F;
        float amp = (za > 20.f ? za : log1pf(expf(za))) + 0.1f;
        float term = (r16 < 8) ? (cosf(ph) + sinf(ph)) * amp : 0.f;
        term += __shfl_xor(term, 1);
        term += __shfl_xor(term, 2);
        term += __shfl_xor(term, 4);
        if (r16 == 0) s[rowbase + q * 4 + j] = term;
    }
}

// ---------------- 256x256 bf16 MFMA GEMM: round-5 4-phase schedule + swapped operands ----------------
// Main loop schedule is the measured-best (171us) round-5 structure, verbatim.
// Only change: mfma(bF, aF) so the C-fragment has COLUMNS lane-local:
//   thread (q,r16): row = brow + wm*128 + (ci>>2)*64 + (ci&3)*16 + r16, col = bcol + wn*64 + nf*16 + q*4 + j
// -> vectorized stores (8B bf16 / 16B f32), vectorized resid loads, no scalar RMW.
// LDS [slot][kh][256 rows][32 k]; 16B-unit XOR swizzle phys_q = q ^ ((row>>1)&3) (conflicts=0).
__device__ __forceinline__ void stage_unit(const unsigned short* __restrict__ src,
                                           unsigned short* dst, int tid) {
    gload_lds16(src,                     dst + tid * 8);
    gload_lds16(src + (size_t)128 * DIM, dst + (tid + 512) * 8);
}

template <int EPI>
__global__ __launch_bounds__(512, 2) void k_gemm256(const unsigned short* __restrict__ A,
                                                    const unsigned short* __restrict__ Bt,
                                                    const float* __restrict__ bias,
                                                    const float* __restrict__ sc,
                                                    const unsigned short* __restrict__ residbf,
                                                    float* __restrict__ C,
                                                    unsigned short* __restrict__ Cbf,
                                                    float* __restrict__ part) {
    __shared__ __align__(16) unsigned short As[2][2][256 * 32];
    __shared__ __align__(16) unsigned short Bs[2][2][256 * 32];
    __shared__ float colsum[2][256];
    const int tid = threadIdx.x;
    const int w = tid >> 6, lane = tid & 63;
    const int wm = w >> 2, wn = w & 3;
    const int r16 = lane & 15, q = lane >> 4;

    int bid = blockIdx.x;
    int wgs = (bid & 7) * 64 + (bid >> 3);        // bijective XCD swizzle (512 % 8 == 0)
    int tm = wgs >> 3, tn = wgs & 7;
    int brow = tm * 256, bcol = tn * 256;

    const int kq = ((tid & 3) ^ ((tid >> 3) & 3)) * 8;
    const unsigned short* pA = A  + (size_t)(brow + (tid >> 2)) * DIM + kq;
    const unsigned short* pB = Bt + (size_t)(bcol + (tid >> 2)) * DIM + kq;

    const int qs8 = (q ^ ((r16 >> 1) & 3)) * 8;
    const int offA = (wm * 128 + r16) * 32 + qs8;
    const int offB = (wn * 64  + r16) * 32 + qs8;

    f32x4 acc[4][8] = {};   // [nf][ci]; ci = chalf*4 + i

    // prologue: A-K0(0), B-K0(0), A-K1(0), B-K1(0), A-K0(1) = 10 loads in flight
    stage_unit(pA,      &As[0][0][0], tid);
    stage_unit(pB,      &Bs[0][0][0], tid);
    stage_unit(pA + 32, &As[0][1][0], tid);
    stage_unit(pB + 32, &Bs[0][1][0], tid);
    stage_unit(pA + 64, &As[1][0][0], tid);
    asm volatile("s_waitcnt vmcnt(6)" ::: "memory");    // K0(0) pair landed
    __builtin_amdgcn_s_barrier();

    for (int t = 0; t < NT; ++t) {
        const int s = t & 1;
        unsigned short* A0 = &As[s][0][0];
        unsigned short* A1 = &As[s][1][0];
        unsigned short* B0 = &Bs[s][0][0];
        unsigned short* B1 = &Bs[s][1][0];
        unsigned short* nA1 = &As[s ^ 1][1][0];
        unsigned short* nB0 = &Bs[s ^ 1][0][0];
        unsigned short* nB1 = &Bs[s ^ 1][1][0];
        const unsigned short* pAn = pA + (t + 1) * 64;  // phantom tail reads stay in ws
        const unsigned short* pBn = pB + (t + 1) * 64;

        bf16x8 aF[4], bF[4];
        // ---- phase 0: (C0, K0) ----
#pragma unroll
        for (int i = 0; i < 4; i++) aF[i] = *(const bf16x8*)(A0 + offA + i * 512);
#pragma unroll
        for (int i = 0; i < 4; i++) bF[i] = *(const bf16x8*)(B0 + offB + i * 512);
        stage_unit(pBn, nB0, tid);
        __builtin_amdgcn_s_barrier();
        __builtin_amdgcn_s_setprio(1);
#pragma unroll
        for (int n = 0; n < 4; n++)
#pragma unroll
            for (int i = 0; i < 4; i++)
                acc[n][i] = __builtin_amdgcn_mfma_f32_16x16x32_bf16(bF[n], aF[i], acc[n][i], 0, 0, 0);
        __builtin_amdgcn_s_setprio(0);
        __builtin_amdgcn_s_barrier();

        // ---- phase 1: (C1, K0), B frags reused from registers ----
#pragma unroll
        for (int i = 0; i < 4; i++) aF[i] = *(const bf16x8*)(A0 + offA + 2048 + i * 512);
        stage_unit(pAn + 32, nA1, tid);
        __builtin_amdgcn_s_barrier();
        __builtin_amdgcn_s_setprio(1);
#pragma unroll
        for (int n = 0; n < 4; n++)
#pragma unroll
            for (int i = 0; i < 4; i++)
                acc[n][4 + i] = __builtin_amdgcn_mfma_f32_16x16x32_bf16(bF[n], aF[i], acc[n][4 + i], 0, 0, 0);
        __builtin_amdgcn_s_setprio(0);
        asm volatile("s_waitcnt vmcnt(6)" ::: "memory"); // K1(t) pair landed before phase 2
        __builtin_amdgcn_s_barrier();

        // ---- phase 2: (C0, K1) ----
#pragma unroll
        for (int i = 0; i < 4; i++) aF[i] = *(const bf16x8*)(A1 + offA + i * 512);
#pragma unroll
        for (int i = 0; i < 4; i++) bF[i] = *(const bf16x8*)(B1 + offB + i * 512);
        stage_unit(pBn + 32, nB1, tid);
        __builtin_amdgcn_s_barrier();
        __builtin_amdgcn_s_setprio(1);
#pragma unroll
        for (int n = 0; n < 4; n++)
#pragma unroll
            for (int i = 0; i < 4; i++)
                acc[n][i] = __builtin_amdgcn_mfma_f32_16x16x32_bf16(bF[n], aF[i], acc[n][i], 0, 0, 0);
        __builtin_amdgcn_s_setprio(0);
        __builtin_amdgcn_s_barrier();

        // ---- phase 3: (C1, K1) ----
#pragma unroll
        for (int i = 0; i < 4; i++) aF[i] = *(const bf16x8*)(A1 + offA + 2048 + i * 512);
        stage_unit(pA + (t + 2) * 64, A0, tid);          // overwrite own slot K0 (last read phase 1)
        __builtin_amdgcn_s_barrier();
        __builtin_amdgcn_s_setprio(1);
#pragma unroll
        for (int n = 0; n < 4; n++)
#pragma unroll
            for (int i = 0; i < 4; i++)
                acc[n][4 + i] = __builtin_amdgcn_mfma_f32_16x16x32_bf16(bF[n], aF[i], acc[n][4 + i], 0, 0, 0);
        __builtin_amdgcn_s_setprio(0);
        asm volatile("s_waitcnt vmcnt(6)" ::: "memory"); // K0(t+1) pair landed before next phase 0
        __builtin_amdgcn_s_barrier();
    }
    asm volatile("s_waitcnt vmcnt(0)" ::: "memory");      // retire phantom tail gloads

    // epilogue (swapped frag): row = brow + wm*128 + (ci>>2)*64 + (ci&3)*16 + r16
    //                          col = bcol + wn*64 + nf*16 + q*4 + j
    float cs[4][4] = {};
#pragma unroll
    for (int nf = 0; nf < 4; nf++) {
        const int c0 = bcol + wn * 64 + nf * 16 + q * 4;
        const f32x4 b4 = *(const f32x4*)(bias + c0);
#pragma unroll
        for (int ci = 0; ci < 8; ci++) {
            const int r = brow + wm * 128 + ((ci >> 2) << 6) + ((ci & 3) << 4) + r16;
            if (EPI == 0) {
                const float scr = sc[r];
                ushort4_t o;
#pragma unroll
                for (int j = 0; j < 4; j++) {
                    float v = (acc[nf][ci][j] + b4[j]) * scr;
                    cs[nf][j] += v;
                    o[j] = f2bf(v);
                }
                *(ushort4_t*)(Cbf + (size_t)r * DIM + c0) = o;          // 8B store
            } else {
                ushort4_t rsd = *(const ushort4_t*)(residbf + (size_t)r * DIM + c0);
                f32x4 v;
#pragma unroll
                for (int j = 0; j < 4; j++) v[j] = acc[nf][ci][j] + b4[j] + bf2f(rsd[j]);
                *(f32x4*)(C + (size_t)r * DIM + c0) = v;                // 16B store
            }
        }
    }
    if (EPI == 0) {   // fused scan_partial: reduce over rows (lane bits 0-3 = r16) then wm
#pragma unroll
        for (int nf = 0; nf < 4; nf++)
#pragma unroll
            for (int j = 0; j < 4; j++) {
                float v = cs[nf][j];
                v += __shfl_xor(v, 1);
                v += __shfl_xor(v, 2);
                v += __shfl_xor(v, 4);
                v += __shfl_xor(v, 8);
                cs[nf][j] = v;
            }
        if (r16 == 0) {
#pragma unroll
            for (int nf = 0; nf < 4; nf++) {
                f32x4 o;
#pragma unroll
                for (int j = 0; j < 4; j++) o[j] = cs[nf][j];
                *(f32x4*)(&colsum[wm][wn * 64 + nf * 16 + q * 4]) = o;
            }
        }
        __syncthreads();
        if (tid < 256)
            part[(size_t)(brow >> 8) * DIM + bcol + tid] = colsum[0][tid] + colsum[1][tid];
    }
}

// ---------------- cumsum over L: chunk-offset scan + apply ----------------
__global__ __launch_bounds__(256) void k_scan_offsets(float* __restrict__ part) {
    int tid = blockIdx.x * 256 + threadIdx.x;  // (b, d)
    int d = tid & (DIM - 1);
    int b = tid >> 11;
    float run = 0.f;
    for (int ch = 0; ch < NCH; ch++) {
        size_t idx = ((size_t)b * NCH + ch) * DIM + d;
        float v = part[idx];
        part[idx] = run;
        run += v;
    }
}

__global__ __launch_bounds__(256) void k_scan_apply(const unsigned short* __restrict__ boundbf,
                                                    const float* __restrict__ part,
                                                    float* __restrict__ ret) {
    int tid = blockIdx.x * 256 + threadIdx.x;
    int d = tid & (DIM - 1);
    int ch = (tid >> 11) & (NCH - 1);
    int b = tid >> 15;
    float run = part[tid];
    size_t base = ((size_t)b * LSEQ + (size_t)ch * CHL) * DIM + d;
    const unsigned short* p = boundbf + base;
    float* o = ret + base;
    for (int i = 0; i < CHL; i++) {
        run += bf2f(p[(size_t)i * DIM]);
        o[(size_t)i * DIM] = run;
    }
}

// ---------------- LayerNorm(retrieved/64) -> h bf16 ----------------
__global__ __launch_bounds__(256) void k_lnorm(const float* __restrict__ ret,
                                               const float* __restrict__ g,
                                               const float* __restrict__ bta,
                                               unsigned short* __restrict__ h) {
    int row = blockIdx.x, t = threadIdx.x;
    const float4* r4 = (const float4*)(ret + (size_t)row * DIM);
    float4 v0 = r4[2 * t], v1 = r4[2 * t + 1];
    const float scl = 1.0f / 64.0f;   // 1/sqrt(L)
    v0.x *= scl; v0.y *= scl; v0.z *= scl; v0.w *= scl;
    v1.x *= scl; v1.y *= scl; v1.z *= scl; v1.w *= scl;
    float sum = v0.x + v0.y + v0.z + v0.w + v1.x + v1.y + v1.z + v1.w;
    float ss  = v0.x*v0.x + v0.y*v0.y + v0.z*v0.z + v0.w*v0.w
              + v1.x*v1.x + v1.y*v1.y + v1.z*v1.z + v1.w*v1.w;
#pragma unroll
    for (int off = 32; off; off >>= 1) { sum += __shfl_down(sum, off); ss += __shfl_down(ss, off); }
    __shared__ float red[4][2];
    __shared__ float mu_s, rstd_s;
    int w = t >> 6, lane = t & 63;
    if (lane == 0) { red[w][0] = sum; red[w][1] = ss; }
    __syncthreads();
    if (t == 0) {
        float S = red[0][0] + red[1][0] + red[2][0] + red[3][0];
        float Q = red[0][1] + red[1][1] + red[2][1] + red[3][1];
        float mu = S / DIM;
        float var = Q / DIM - mu * mu;
        mu_s = mu; rstd_s = rsqrtf(var + 1e-5f);
    }
    __syncthreads();
    float mu = mu_s, rstd = rstd_s;
    f32x8 gv = *(const f32x8*)(g + t * 8);
    f32x8 bv = *(const f32x8*)(bta + t * 8);
    float vv[8] = { v0.x, v0.y, v0.z, v0.w, v1.x, v1.y, v1.z, v1.w };
    ushort8 o;
#pragma unroll
    for (int j = 0; j < 8; j++) o[j] = f2bf((vv[j] - mu) * rstd * gv[j] + bv[j]);
    *(ushort8*)(h + (size_t)row * DIM + t * 8) = o;
}

extern "C" void kernel_launch(void* const* d_in, const int* in_sizes, int n_in,
                              void* d_out, int out_size, void* d_ws, size_t ws_size,
                              hipStream_t stream) {
    const float* x   = (const float*)d_in[0];
    const float* Wp  = (const float*)d_in[1];
    const float* bp  = (const float*)d_in[2];
    const float* Wa  = (const float*)d_in[3];
    const float* ba  = (const float*)d_in[4];
    const float* Wv  = (const float*)d_in[5];
    const float* bv  = (const float*)d_in[6];
    const float* lng = (const float*)d_in[7];
    const float* lnb = (const float*)d_in[8];
    const float* Wo  = (const float*)d_in[9];
    const float* bo  = (const float*)d_in[10];
    float* out = (float*)d_out;

    char* ws = (char*)d_ws;
    unsigned short* x_bf  = (unsigned short*)ws; ws += (size_t)NTOK * DIM * 2;   // bf16 x (A0, resid1)
    unsigned short* h_bf  = (unsigned short*)ws; ws += (size_t)NTOK * DIM * 2;   // lnorm out (A1)
    unsigned short* WvT   = (unsigned short*)ws; ws += (size_t)DIM * DIM * 2;
    unsigned short* WoT   = (unsigned short*)ws; ws += (size_t)DIM * DIM * 2;
    unsigned short* WpaT  = (unsigned short*)ws; ws += (size_t)16 * DIM * 2;
    float* svec           = (float*)ws;          ws += (size_t)NTOK * 4;
    unsigned short* bound = (unsigned short*)ws; ws += (size_t)NTOK * DIM * 2;   // bf16 bound
    float* part           = (float*)ws;          ws += (size_t)BATCH * NCH * DIM * 4;
    float* ret            = out;                 // stage retrieved in d_out, overwritten by GEMM1

    dim3 tb(32, 8);
    k_transpose<<<dim3(64, 64), tb, 0, stream>>>(Wv, WvT);
    k_transpose<<<dim3(64, 64), tb, 0, stream>>>(Wo, WoT);
    k_prep_wpa<<<128, 256, 0, stream>>>(Wp, Wa, WpaT);
    k_sproj_mfma<<<NTOK / 64, 256, 0, stream>>>(x, WpaT, bp, ba, svec, x_bf);

    k_gemm256<0><<<512, 512, 0, stream>>>(x_bf, WvT, bv, svec, nullptr, nullptr, bound, part);

    k_scan_offsets<<<BATCH * DIM / 256, 256, 0, stream>>>(part);
    k_scan_apply<<<BATCH * NCH * DIM / 256, 256, 0, stream>>>(bound, part, ret);

    k_lnorm<<<NTOK, 256, 0, stream>>>(ret, lng, lnb, h_bf);

    k_gemm256<1><<<512, 512, 0, stream>>>(h_bf, WoT, bo, nullptr, x_bf, out, nullptr, nullptr);
}

// Round 10
// 401.352 us; speedup vs baseline: 1.1896x; 1.1487x over previous
//
#include <hip/hip_runtime.h>

#define DIM   2048
#define LSEQ  4096
#define BATCH 4
#define NTOK  (BATCH*LSEQ)        // 16384
#define NCH   16
#define CHL   (LSEQ/NCH)          // 256
#define PI_F  3.14159265358979f
#define NT    (DIM/64)            // 32 K-tiles of 64

typedef __bf16 bf16x8 __attribute__((ext_vector_type(8)));
typedef float  f32x4  __attribute__((ext_vector_type(4)));
typedef float  f32x8  __attribute__((ext_vector_type(8)));
typedef unsigned short ushort4_t __attribute__((ext_vector_type(4)));
typedef unsigned short ushort8 __attribute__((ext_vector_type(8)));

__device__ __forceinline__ unsigned short f2bf(float f) {
    unsigned int u = __float_as_uint(f);
    u += 0x7fffu + ((u >> 16) & 1u);       // round-to-nearest-even
    return (unsigned short)(u >> 16);
}
__device__ __forceinline__ float bf2f(unsigned short u) {
    return __uint_as_float((unsigned int)u << 16);
}

__device__ __forceinline__ void gload_lds16(const void* g, void* l) {
    __builtin_amdgcn_global_load_lds(
        (const __attribute__((address_space(1))) void*)g,
        (__attribute__((address_space(3))) void*)l, 16, 0, 0);
}

// ---------------- W [K][N] fp32 -> W^T [N][K] bf16 ----------------
__global__ __launch_bounds__(256) void k_transpose(const float* __restrict__ src,
                                                   unsigned short* __restrict__ dst) {
    __shared__ float tile[32][33];
    int tx = threadIdx.x, ty = threadIdx.y;
    int k0 = blockIdx.y * 32, n0 = blockIdx.x * 32;
#pragma unroll
    for (int r = 0; r < 4; r++)
        tile[ty + r * 8][tx] = src[(size_t)(k0 + ty + r * 8) * DIM + n0 + tx];
    __syncthreads();
#pragma unroll
    for (int r = 0; r < 4; r++)
        dst[(size_t)(n0 + ty + r * 8) * DIM + k0 + tx] = f2bf(tile[tx][ty + r * 8]);
}

// ---------------- W_paT[16][2048] bf16 : rows 0..7 = Wp cols, 8..15 = Wa cols ----------------
__global__ __launch_bounds__(256) void k_prep_wpa(const float* __restrict__ Wp,
                                                  const float* __restrict__ Wa,
                                                  unsigned short* __restrict__ WpaT) {
    int idx = blockIdx.x * 256 + threadIdx.x;        // 128 blocks x 256 = 32768
    int p = idx >> 11, k = idx & (DIM - 1);
    float v = (p < 8) ? Wp[(size_t)k * 8 + p] : Wa[(size_t)k * 8 + (p - 8)];
    WpaT[idx] = f2bf(v);
}

// ---- sproj via MFMA: Z = x @ [Wp|Wa] (16-wide), fused x->bf16 emit ----
__global__ __launch_bounds__(256) void k_sproj_mfma(const float* __restrict__ x,
                                                    const unsigned short* __restrict__ WpaT,
                                                    const float* __restrict__ bp,
                                                    const float* __restrict__ ba,
                                                    float* __restrict__ s,
                                                    unsigned short* __restrict__ xbf) {
    const int t = threadIdx.x;
    const int w = t >> 6, l = t & 63;
    const int r16 = l & 15, q = l >> 4;
    const int rowbase = blockIdx.x * 64 + w * 16;
    const float* xr = x + (size_t)(rowbase + r16) * DIM + q * 8;
    unsigned short* xw = xbf + (size_t)(rowbase + r16) * DIM + q * 8;
    const unsigned short* wrow = WpaT + r16 * DIM + q * 8;

    f32x4 acc = {};
#pragma unroll 8
    for (int ks = 0; ks < 64; ks++) {
        f32x8 xv = *(const f32x8*)(xr + ks * 32);
        ushort8 xo;
#pragma unroll
        for (int j = 0; j < 8; j++) xo[j] = f2bf(xv[j]);
        *(ushort8*)(xw + ks * 32) = xo;
        bf16x8 av = *(const bf16x8*)&xo;
        bf16x8 bv = *(const bf16x8*)(wrow + ks * 32);
        acc = __builtin_amdgcn_mfma_f32_16x16x32_bf16(av, bv, acc, 0, 0, 0);
    }
    // acc[j] = Z[rowbase + q*4 + j][col=r16]; cols 0..7 = zp, 8..15 = za
    const float bpv = bp[r16 & 7], bav = ba[r16 & 7];
#pragma unroll
    for (int j = 0; j < 4; j++) {
        float z = acc[j];
        float zo = __shfl_xor(z, 8);            // partner col r16^8
        float zp = z + bpv, za = zo + bav;
        float ph = tanhf(zp) * PI_F;
        float amp = (za > 20.f ? za : log1pf(expf(za))) + 0.1f;
        float term = (r16 < 8) ? (cosf(ph) + sinf(ph)) * amp : 0.f;
        term += __shfl_xor(term, 1);
        term += __shfl_xor(term, 2);
        term += __shfl_xor(term, 4);
        if (r16 == 0) s[rowbase + q * 4 + j] = term;
    }
}

// ---------------- 256x256 bf16 MFMA GEMM: round-5 best schedule (171us), verbatim ----------------
// 4 phases/K-tile, mfma(aF,bF), acc[8][4]; LDS [slot][kh][256][32], XOR swizzle (conflicts=0).
// Epilogue dtype-only edits: EPI0 writes bound as bf16 + fused 256-row colsum -> part;
// EPI1 reads resid as bf16, writes fp32 out.
__device__ __forceinline__ void stage_unit(const unsigned short* __restrict__ src,
                                           unsigned short* dst, int tid) {
    gload_lds16(src,                     dst + tid * 8);
    gload_lds16(src + (size_t)128 * DIM, dst + (tid + 512) * 8);
}

template <int EPI>
__global__ __launch_bounds__(512, 2) void k_gemm256(const unsigned short* __restrict__ A,
                                                    const unsigned short* __restrict__ Bt,
                                                    const float* __restrict__ bias,
                                                    const float* __restrict__ sc,
                                                    const unsigned short* __restrict__ residbf,
                                                    float* __restrict__ C,
                                                    unsigned short* __restrict__ Cbf,
                                                    float* __restrict__ part) {
    __shared__ __align__(16) unsigned short As[2][2][256 * 32];
    __shared__ __align__(16) unsigned short Bs[2][2][256 * 32];
    __shared__ float colsum[2][256];
    const int tid = threadIdx.x;
    const int w = tid >> 6, lane = tid & 63;
    const int wm = w >> 2, wn = w & 3;
    const int r16 = lane & 15, q = lane >> 4;

    int bid = blockIdx.x;
    int wgs = (bid & 7) * 64 + (bid >> 3);        // bijective XCD swizzle (512 % 8 == 0)
    int tm = wgs >> 3, tn = wgs & 7;
    int brow = tm * 256, bcol = tn * 256;

    const int kq = ((tid & 3) ^ ((tid >> 3) & 3)) * 8;
    const unsigned short* pA = A  + (size_t)(brow + (tid >> 2)) * DIM + kq;
    const unsigned short* pB = Bt + (size_t)(bcol + (tid >> 2)) * DIM + kq;

    const int qs8 = (q ^ ((r16 >> 1) & 3)) * 8;
    const int offA = (wm * 128 + r16) * 32 + qs8;
    const int offB = (wn * 64  + r16) * 32 + qs8;

    f32x4 acc[8][4] = {};

    // prologue: A-K0(0), B-K0(0), A-K1(0), B-K1(0), A-K0(1) = 10 loads in flight
    stage_unit(pA,      &As[0][0][0], tid);
    stage_unit(pB,      &Bs[0][0][0], tid);
    stage_unit(pA + 32, &As[0][1][0], tid);
    stage_unit(pB + 32, &Bs[0][1][0], tid);
    stage_unit(pA + 64, &As[1][0][0], tid);
    asm volatile("s_waitcnt vmcnt(6)" ::: "memory");    // K0(0) pair landed
    __builtin_amdgcn_s_barrier();

    for (int t = 0; t < NT; ++t) {
        const int s = t & 1;
        unsigned short* A0 = &As[s][0][0];
        unsigned short* A1 = &As[s][1][0];
        unsigned short* B0 = &Bs[s][0][0];
        unsigned short* B1 = &Bs[s][1][0];
        unsigned short* nA1 = &As[s ^ 1][1][0];
        unsigned short* nB0 = &Bs[s ^ 1][0][0];
        unsigned short* nB1 = &Bs[s ^ 1][1][0];
        const unsigned short* pAn = pA + (t + 1) * 64;  // phantom tail reads stay in ws
        const unsigned short* pBn = pB + (t + 1) * 64;

        bf16x8 aF[4], bF[4];
        // ---- phase 0: (C0, K0) ----
#pragma unroll
        for (int i = 0; i < 4; i++) aF[i] = *(const bf16x8*)(A0 + offA + i * 512);
#pragma unroll
        for (int i = 0; i < 4; i++) bF[i] = *(const bf16x8*)(B0 + offB + i * 512);
        stage_unit(pBn, nB0, tid);
        __builtin_amdgcn_s_barrier();
        __builtin_amdgcn_s_setprio(1);
#pragma unroll
        for (int i = 0; i < 4; i++)
#pragma unroll
            for (int n = 0; n < 4; n++)
                acc[i][n] = __builtin_amdgcn_mfma_f32_16x16x32_bf16(aF[i], bF[n], acc[i][n], 0, 0, 0);
        __builtin_amdgcn_s_setprio(0);
        __builtin_amdgcn_s_barrier();

        // ---- phase 1: (C1, K0), B frags reused from registers ----
#pragma unroll
        for (int i = 0; i < 4; i++) aF[i] = *(const bf16x8*)(A0 + offA + 2048 + i * 512);
        stage_unit(pAn + 32, nA1, tid);
        __builtin_amdgcn_s_barrier();
        __builtin_amdgcn_s_setprio(1);
#pragma unroll
        for (int i = 0; i < 4; i++)
#pragma unroll
            for (int n = 0; n < 4; n++)
                acc[4 + i][n] = __builtin_amdgcn_mfma_f32_16x16x32_bf16(aF[i], bF[n], acc[4 + i][n], 0, 0, 0);
        __builtin_amdgcn_s_setprio(0);
        asm volatile("s_waitcnt vmcnt(6)" ::: "memory"); // K1(t) pair landed before phase 2
        __builtin_amdgcn_s_barrier();

        // ---- phase 2: (C0, K1) ----
#pragma unroll
        for (int i = 0; i < 4; i++) aF[i] = *(const bf16x8*)(A1 + offA + i * 512);
#pragma unroll
        for (int i = 0; i < 4; i++) bF[i] = *(const bf16x8*)(B1 + offB + i * 512);
        stage_unit(pBn + 32, nB1, tid);
        __builtin_amdgcn_s_barrier();
        __builtin_amdgcn_s_setprio(1);
#pragma unroll
        for (int i = 0; i < 4; i++)
#pragma unroll
            for (int n = 0; n < 4; n++)
                acc[i][n] = __builtin_amdgcn_mfma_f32_16x16x32_bf16(aF[i], bF[n], acc[i][n], 0, 0, 0);
        __builtin_amdgcn_s_setprio(0);
        __builtin_amdgcn_s_barrier();

        // ---- phase 3: (C1, K1) ----
#pragma unroll
        for (int i = 0; i < 4; i++) aF[i] = *(const bf16x8*)(A1 + offA + 2048 + i * 512);
        stage_unit(pA + (t + 2) * 64, A0, tid);          // overwrite own slot K0 (last read phase 1)
        __builtin_amdgcn_s_barrier();
        __builtin_amdgcn_s_setprio(1);
#pragma unroll
        for (int i = 0; i < 4; i++)
#pragma unroll
            for (int n = 0; n < 4; n++)
                acc[4 + i][n] = __builtin_amdgcn_mfma_f32_16x16x32_bf16(aF[i], bF[n], acc[4 + i][n], 0, 0, 0);
        __builtin_amdgcn_s_setprio(0);
        asm volatile("s_waitcnt vmcnt(6)" ::: "memory"); // K0(t+1) pair landed before next phase 0
        __builtin_amdgcn_s_barrier();
    }
    asm volatile("s_waitcnt vmcnt(0)" ::: "memory");      // retire phantom tail gloads

    // epilogue: frag row = q*4+j, col = r16 (verified convention)
    float cs[4] = {0.f, 0.f, 0.f, 0.f};
#pragma unroll
    for (int mf = 0; mf < 8; mf++) {
        int r0 = brow + wm * 128 + mf * 16 + q * 4;
#pragma unroll
        for (int nf = 0; nf < 4; nf++) {
            int c = bcol + wn * 64 + nf * 16 + r16;
            float bc = bias[c];
#pragma unroll
            for (int j = 0; j < 4; j++) {
                int r = r0 + j;
                float v = acc[mf][nf][j] + bc;
                if (EPI == 0) {
                    v *= sc[r];
                    cs[nf] += v;
                    Cbf[(size_t)r * DIM + c] = f2bf(v);
                } else {
                    v += bf2f(residbf[(size_t)r * DIM + c]);
                    C[(size_t)r * DIM + c] = v;
                }
            }
        }
    }
    if (EPI == 0) {   // fused scan_partial: column sums of this 256x256 tile
#pragma unroll
        for (int nf = 0; nf < 4; nf++) {
            float v = cs[nf];
            v += __shfl_xor(v, 16);           // reduce over q
            v += __shfl_xor(v, 32);
            if (q == 0) colsum[wm][wn * 64 + nf * 16 + r16] = v;
        }
        __syncthreads();
        if (tid < 256)
            part[(size_t)(brow >> 8) * DIM + bcol + tid] = colsum[0][tid] + colsum[1][tid];
    }
}

// ---------------- cumsum over L: chunk-offset scan + in-place apply (bf16) ----------------
__global__ __launch_bounds__(256) void k_scan_offsets(float* __restrict__ part) {
    int tid = blockIdx.x * 256 + threadIdx.x;  // (b, d)
    int d = tid & (DIM - 1);
    int b = tid >> 11;
    float run = 0.f;
    for (int ch = 0; ch < NCH; ch++) {
        size_t idx = ((size_t)b * NCH + ch) * DIM + d;
        float v = part[idx];
        part[idx] = run;
        run += v;
    }
}

__global__ __launch_bounds__(256) void k_scan_apply(unsigned short* __restrict__ boundbf,
                                                    const float* __restrict__ part) {
    int tid = blockIdx.x * 256 + threadIdx.x;
    int d = tid & (DIM - 1);
    int ch = (tid >> 11) & (NCH - 1);
    int b = tid >> 15;
    float run = part[tid];
    unsigned short* p = boundbf + ((size_t)b * LSEQ + (size_t)ch * CHL) * DIM + d;
    for (int i = 0; i < CHL; i++) {             // in-place: thread owns this column slice
        run += bf2f(p[(size_t)i * DIM]);
        p[(size_t)i * DIM] = f2bf(run);
    }
}

// ---------------- LayerNorm(retrieved_bf/64) -> h bf16 ----------------
__global__ __launch_bounds__(256) void k_lnorm(const unsigned short* __restrict__ retbf,
                                               const float* __restrict__ g,
                                               const float* __restrict__ bta,
                                               unsigned short* __restrict__ h) {
    int row = blockIdx.x, t = threadIdx.x;
    ushort8 rv = *(const ushort8*)(retbf + (size_t)row * DIM + t * 8);
    const float scl = 1.0f / 64.0f;   // 1/sqrt(L)
    float vv[8];
    float sum = 0.f, ss = 0.f;
#pragma unroll
    for (int j = 0; j < 8; j++) {
        vv[j] = bf2f(rv[j]) * scl;
        sum += vv[j];
        ss  += vv[j] * vv[j];
    }
#pragma unroll
    for (int off = 32; off; off >>= 1) { sum += __shfl_down(sum, off); ss += __shfl_down(ss, off); }
    __shared__ float red[4][2];
    __shared__ float mu_s, rstd_s;
    int w = t >> 6, lane = t & 63;
    if (lane == 0) { red[w][0] = sum; red[w][1] = ss; }
    __syncthreads();
    if (t == 0) {
        float S = red[0][0] + red[1][0] + red[2][0] + red[3][0];
        float Q = red[0][1] + red[1][1] + red[2][1] + red[3][1];
        float mu = S / DIM;
        float var = Q / DIM - mu * mu;
        mu_s = mu; rstd_s = rsqrtf(var + 1e-5f);
    }
    __syncthreads();
    float mu = mu_s, rstd = rstd_s;
    f32x8 gv = *(const f32x8*)(g + t * 8);
    f32x8 bv = *(const f32x8*)(bta + t * 8);
    ushort8 o;
#pragma unroll
    for (int j = 0; j < 8; j++) o[j] = f2bf((vv[j] - mu) * rstd * gv[j] + bv[j]);
    *(ushort8*)(h + (size_t)row * DIM + t * 8) = o;
}

extern "C" void kernel_launch(void* const* d_in, const int* in_sizes, int n_in,
                              void* d_out, int out_size, void* d_ws, size_t ws_size,
                              hipStream_t stream) {
    const float* x   = (const float*)d_in[0];
    const float* Wp  = (const float*)d_in[1];
    const float* bp  = (const float*)d_in[2];
    const float* Wa  = (const float*)d_in[3];
    const float* ba  = (const float*)d_in[4];
    const float* Wv  = (const float*)d_in[5];
    const float* bv  = (const float*)d_in[6];
    const float* lng = (const float*)d_in[7];
    const float* lnb = (const float*)d_in[8];
    const float* Wo  = (const float*)d_in[9];
    const float* bo  = (const float*)d_in[10];
    float* out = (float*)d_out;

    char* ws = (char*)d_ws;
    unsigned short* x_bf  = (unsigned short*)ws; ws += (size_t)NTOK * DIM * 2;   // bf16 x (A0, resid1)
    unsigned short* h_bf  = (unsigned short*)ws; ws += (size_t)NTOK * DIM * 2;   // lnorm out (A1)
    unsigned short* WvT   = (unsigned short*)ws; ws += (size_t)DIM * DIM * 2;
    unsigned short* WoT   = (unsigned short*)ws; ws += (size_t)DIM * DIM * 2;
    unsigned short* WpaT  = (unsigned short*)ws; ws += (size_t)16 * DIM * 2;
    float* svec           = (float*)ws;          ws += (size_t)NTOK * 4;
    unsigned short* bound = (unsigned short*)ws; ws += (size_t)NTOK * DIM * 2;   // bf16 bound -> retrieved (in-place)
    float* part           = (float*)ws;          ws += (size_t)BATCH * NCH * DIM * 4;

    dim3 tb(32, 8);
    k_transpose<<<dim3(64, 64), tb, 0, stream>>>(Wv, WvT);
    k_transpose<<<dim3(64, 64), tb, 0, stream>>>(Wo, WoT);
    k_prep_wpa<<<128, 256, 0, stream>>>(Wp, Wa, WpaT);
    k_sproj_mfma<<<NTOK / 64, 256, 0, stream>>>(x, WpaT, bp, ba, svec, x_bf);

    k_gemm256<0><<<512, 512, 0, stream>>>(x_bf, WvT, bv, svec, nullptr, nullptr, bound, part);

    k_scan_offsets<<<BATCH * DIM / 256, 256, 0, stream>>>(part);
    k_scan_apply<<<BATCH * NCH * DIM / 256, 256, 0, stream>>>(bound, part);

    k_lnorm<<<NTOK, 256, 0, stream>>>(bound, lng, lnb, h_bf);

    k_gemm256<1><<<512, 512, 0, stream>>>(h_bf, WoT, bo, nullptr, x_bf, out, nullptr, nullptr);
}